// Round 1
// 292.009 us; speedup vs baseline: 1.1690x; 1.1690x over previous
//
#include <hip/hip_runtime.h>
#include <math.h>

// Problem constants
#define Bn 2
#define Vn 6
#define Cn 96
#define Dn 48
#define Hn 48
#define Wn 48
#define THn 96
#define TWn 96
#define EPSf 1e-5f

// packetized geometry: 16B packets of 8 consecutive ci
#define PD 98
#define NCI8 12
// rz:  (((vb*PD+py)*NCI8 + ci8)*PD + px)*8 + e     (bf16, zero-padded halo)
// co1: (((vb*NCI8+co8)*9216 + n)*8 + e             (bf16)
// wAtP:(((tap*NCI8+ci8)*96 + co)*8 + e             (bf16)
// wCP: ((ci8*96 + co)*8 + e                        (bf16)
#define RZ_VB (PD * NCI8 * PD * 8)
#define RZ_BYTES (12 * RZ_VB * 2)                   // 22,127,616

typedef __attribute__((ext_vector_type(8))) short s8v;   // 8 bf16
typedef __attribute__((ext_vector_type(4))) float f4v;   // MFMA acc

__device__ __forceinline__ unsigned short f2bf(float f) {
    unsigned int u = __builtin_bit_cast(unsigned int, f);
    u += 0x7FFFu + ((u >> 16) & 1u);          // RNE
    return (unsigned short)(u >> 16);
}
__device__ __forceinline__ float bf2f(unsigned short h) {
    unsigned int u = ((unsigned int)h) << 16;
    return __builtin_bit_cast(float, u);
}
__device__ __forceinline__ void unpack8(uint4 r, float* f) {
    unsigned int w[4] = {r.x, r.y, r.z, r.w};
#pragma unroll
    for (int j = 0; j < 8; ++j)
        f[j] = bf2f((unsigned short)((w[j >> 1] >> ((j & 1) * 16)) & 0xFFFFu));
}
__device__ __forceinline__ uint4 pack8(const unsigned short* o) {
    uint4 pk;
    pk.x = (unsigned int)o[0] | ((unsigned int)o[1] << 16);
    pk.y = (unsigned int)o[2] | ((unsigned int)o[3] << 16);
    pk.z = (unsigned int)o[4] | ((unsigned int)o[5] << 16);
    pk.w = (unsigned int)o[6] | ((unsigned int)o[7] << 16);
    return pk;
}

// Branchless exact-GELU: erf via Abramowitz-Stegun 7.1.26 (|err| < 1.5e-7,
// far below the bf16 quantization applied to the result). ~12 VALU ops,
// hardware v_rcp_f32 / v_exp_f32, no OCML branches.
__device__ __forceinline__ float gelu_f(float y) {
    float z = y * 0.70710678118654752f;
    float a = fabsf(z);
    float t = __builtin_amdgcn_rcpf(fmaf(0.3275911f, a, 1.0f));
    float e = __builtin_amdgcn_exp2f(-1.4426950408889634f * a * a);
    float p = t * fmaf(t, fmaf(t, fmaf(t, fmaf(t, 1.061405429f,
                                               -1.453152027f),
                                       1.421413741f),
                               -0.284496736f),
                       0.254829592f);
    float er = fmaf(-p, e, 1.0f);            // erf(|z|)
    er = copysignf(er, z);
    return 0.5f * y * (1.0f + er);
}

// ---------------------------------------------------------------------------
// K0: weight prep into packet layouts.
// ---------------------------------------------------------------------------
__global__ __launch_bounds__(256) void k_prep(const float* __restrict__ w1,
                                              const float* __restrict__ w2,
                                              unsigned short* __restrict__ wAtP,
                                              unsigned short* __restrict__ wCP) {
    int i = blockIdx.x * 256 + threadIdx.x;
    if (i < 82944) {                       // 9*12*96*8
        int e = i & 7;
        int u = i >> 3;
        int co = u % 96;
        int u2 = u / 96;                   // tap*12 + ci8
        int ci8 = u2 % NCI8;
        int tap = u2 / NCI8;
        wAtP[i] = f2bf(w1[(co * 96 + ci8 * 8 + e) * 9 + tap]);
    } else if (i < 92160) {
        int j = i - 82944;
        int e = j & 7;
        int u = j >> 3;
        int co = u % 96;
        int ci8 = u / 96;
        wCP[j] = f2bf(w2[co * 96 + ci8 * 8 + e]);
    }
}

// ---------------------------------------------------------------------------
// K0b: tokens fp32 -> bf16 (same layout), coalesced.
// ---------------------------------------------------------------------------
__global__ __launch_bounds__(256) void k_tok(const float* __restrict__ tokens,
                                             unsigned short* __restrict__ tokB) {
    int idx = blockIdx.x * 256 + threadIdx.x;      // 2,654,208 threads
    size_t base = (size_t)idx * 8;
    float4 f0 = *(const float4*)(tokens + base);
    float4 f1 = *(const float4*)(tokens + base + 4);
    unsigned short o[8] = {f2bf(f0.x), f2bf(f0.y), f2bf(f0.z), f2bf(f0.w),
                           f2bf(f1.x), f2bf(f1.y), f2bf(f1.z), f2bf(f1.w)};
    *(uint4*)(&tokB[base]) = pack8(o);
}

// ---------------------------------------------------------------------------
// K1: rotated projection -> featP[vb][y48][ci8][x48][8] bf16.
// iy == y exactly; bilinear in (x,z), mean over 48 z. 8 channels/thread.
// ---------------------------------------------------------------------------
__global__ __launch_bounds__(256) void k_feat(const unsigned short* __restrict__ tokB,
                                              const float* __restrict__ angles,
                                              unsigned short* __restrict__ featP) {
    int idx = blockIdx.x * 256 + threadIdx.x;   // 331,776 total
    int c8i = idx % NCI8;
    int r = idx / NCI8;
    int x = r % Wn; r /= Wn;
    int y = r % Hn; r /= Hn;
    int b = r & 1;
    int v = r >> 1;
    int vb = v * 2 + b;

    float th = angles[v];
    float ct = cosf(th), st = sinf(th);
    float X = (x + 0.5f) * (2.0f / 48.0f) - 1.0f;
    float Zc0 = 0.5f * (2.0f / 48.0f) - 1.0f;
    float ix = 24.0f * (ct * X + st * Zc0) + 23.5f;
    float iz = 24.0f * (-st * X + ct * Zc0) + 23.5f;

    const unsigned short* tb = tokB + (size_t)b * (Dn * Hn * Wn) * Cn + c8i * 8;
    int ybase = y * Wn;

    float af[8] = {0.f, 0.f, 0.f, 0.f, 0.f, 0.f, 0.f, 0.f};
    for (int z = 0; z < Dn; ++z) {
        float x0f = floorf(ix), z0f = floorf(iz);
        float tx = ix - x0f, tz = iz - z0f;
        int x0 = (int)x0f, z0 = (int)z0f;
        float wx[2] = {1.0f - tx, tx};
        float wz[2] = {1.0f - tz, tz};
#pragma unroll
        for (int dz = 0; dz < 2; ++dz) {
            int zc = z0 + dz;
            bool zin = (zc >= 0) && (zc < Dn);
            int zi = min(max(zc, 0), Dn - 1);
            int zoff = zi * (Hn * Wn);
#pragma unroll
            for (int dx = 0; dx < 2; ++dx) {
                int xc = x0 + dx;
                bool xin = (xc >= 0) && (xc < Wn);
                int xi = min(max(xc, 0), Wn - 1);
                float w = wx[dx] * wz[dz] * ((zin && xin) ? 1.0f : 0.0f);
                uint4 raw = *(const uint4*)(tb + (size_t)(zoff + ybase + xi) * Cn);
                float f[8];
                unpack8(raw, f);
#pragma unroll
                for (int j = 0; j < 8; ++j) af[j] += w * f[j];
            }
        }
        ix += st;
        iz += ct;
    }
    const float s = 1.0f / 48.0f;
    unsigned short o[8];
#pragma unroll
    for (int j = 0; j < 8; ++j) o[j] = f2bf(af[j] * s);
    size_t off = (((size_t)vb * Hn + y) * NCI8 + c8i) * Wn + x;
    *(uint4*)(&featP[off * 8]) = pack8(o);
}

// ---------------------------------------------------------------------------
// K2: bilinear resize 48->96 into zero-padded packetized rz. x-fastest lanes:
// coalesced packet reads (2-lane broadcast) and contiguous packet writes.
// ---------------------------------------------------------------------------
__global__ __launch_bounds__(256) void k_resize(const unsigned short* __restrict__ featP,
                                                unsigned short* __restrict__ rz) {
    int idx = blockIdx.x * 256 + threadIdx.x;   // 1,327,104 total
    int x = idx % TWn;
    int r = idx / TWn;
    int c8i = r % NCI8; r /= NCI8;
    int y = r % THn;
    int vb = r / THn;

    float sy = fmaxf(0.5f * (y + 0.5f) - 0.5f, 0.0f);
    int y0 = min((int)sy, Hn - 1);
    int y1 = min(y0 + 1, Hn - 1);
    float ty = sy - (float)y0;
    float sx = fmaxf(0.5f * (x + 0.5f) - 0.5f, 0.0f);
    int x0 = min((int)sx, Wn - 1);
    int x1 = min(x0 + 1, Wn - 1);
    float tx = sx - (float)x0;

    const unsigned short* fb = featP + ((size_t)vb * Hn * NCI8 + c8i) * Wn * 8;
    // row bases for y0/y1 at this c8 plane
    const unsigned short* r0 = fb + (size_t)y0 * (NCI8 * Wn * 8);
    const unsigned short* r1 = fb + (size_t)y1 * (NCI8 * Wn * 8);
    uint4 q00 = *(const uint4*)(r0 + (size_t)x0 * 8);
    uint4 q01 = *(const uint4*)(r0 + (size_t)x1 * 8);
    uint4 q10 = *(const uint4*)(r1 + (size_t)x0 * 8);
    uint4 q11 = *(const uint4*)(r1 + (size_t)x1 * 8);
    float f00[8], f01[8], f10[8], f11[8];
    unpack8(q00, f00); unpack8(q01, f01); unpack8(q10, f10); unpack8(q11, f11);

    float w00 = (1.f - ty) * (1.f - tx), w01 = (1.f - ty) * tx;
    float w10 = ty * (1.f - tx),         w11 = ty * tx;

    unsigned short o[8];
#pragma unroll
    for (int j = 0; j < 8; ++j)
        o[j] = f2bf(w00 * f00[j] + w01 * f01[j] + w10 * f10[j] + w11 * f11[j]);

    size_t off = (((size_t)vb * PD + (y + 1)) * NCI8 + c8i) * PD + (x + 1);
    *(uint4*)(&rz[off * 8]) = pack8(o);
}

// ---------------------------------------------------------------------------
// K3: conv1 3x3 SAME, implicit GEMM bf16 MFMA 16x16x32. ZERO LDS.
// Wave = 32 n (2 tiles) x 96 co -> 864 blocks (3.4 waves/SIMD) for latency
// hiding; i=2 keeps 2x in-register A-fragment reuse. 324 MFMA/wave.
// ---------------------------------------------------------------------------
__global__ __launch_bounds__(256) void k_conv1(const unsigned short* __restrict__ rz,
                                               const unsigned short* __restrict__ wAtP,
                                               unsigned short* __restrict__ co1) {
    int blk = blockIdx.x;
    int n0 = blk * 128;                // 9216 % 128 == 0 -> single vb
    int vb = n0 / 9216;
    int nl0 = n0 - vb * 9216;

    int t = threadIdx.x;
    int wv = t >> 6;
    int l = t & 63;
    int l15 = l & 15, q = l >> 4;

    int nt0 = nl0 + wv * 32;
    int nl[2];
    const unsigned short* pB[2];
#pragma unroll
    for (int i = 0; i < 2; ++i) {
        nl[i] = nt0 + i * 16 + l15;
        int y = nl[i] / 96, x = nl[i] - y * 96;
        // base at (py=y, ci8=0, px=x); taps add (dy*NCI8*PD + ci8*PD + dx)*8
        pB[i] = rz + ((((size_t)vb * PD + y) * NCI8) * PD + x) * 8;
    }

    f4v acc[2][6];
#pragma unroll
    for (int i = 0; i < 2; ++i)
#pragma unroll
        for (int mt = 0; mt < 6; ++mt) acc[i][mt] = (f4v){0.f, 0.f, 0.f, 0.f};

#pragma unroll
    for (int ks = 0; ks < 3; ++ks) {
        int ci8 = ks * 4 + q;
        const unsigned short* pb0 = pB[0] + (size_t)ci8 * (PD * 8);
        const unsigned short* pb1 = pB[1] + (size_t)ci8 * (PD * 8);
        const unsigned short* pa = wAtP + ((size_t)ci8 * 96 + l15) * 8;
#pragma unroll
        for (int tap = 0; tap < 9; ++tap) {
            int dy = tap / 3, dx = tap % 3;
            size_t toff = ((size_t)dy * (NCI8 * PD) + dx) * 8;   // const
            s8v b0 = *(const s8v*)(pb0 + toff);
            s8v b1 = *(const s8v*)(pb1 + toff);
            const unsigned short* ap = pa + (size_t)tap * (NCI8 * 96 * 8);
#pragma unroll
            for (int mt = 0; mt < 6; ++mt) {
                s8v a = *(const s8v*)(ap + (size_t)mt * (16 * 8));
                acc[0][mt] = __builtin_amdgcn_mfma_f32_16x16x32_bf16(a, b0, acc[0][mt], 0, 0, 0);
                acc[1][mt] = __builtin_amdgcn_mfma_f32_16x16x32_bf16(a, b1, acc[1][mt], 0, 0, 0);
            }
        }
    }

    // store to packetized co1 (no stats here)
#pragma unroll
    for (int i = 0; i < 2; ++i) {
#pragma unroll
        for (int mt = 0; mt < 6; ++mt) {
            int co0 = mt * 16 + q * 4;         // D: row(m)=q*4+reg, col(n)=l15
            ushort4 pk;
            pk.x = f2bf(acc[i][mt][0]); pk.y = f2bf(acc[i][mt][1]);
            pk.z = f2bf(acc[i][mt][2]); pk.w = f2bf(acc[i][mt][3]);
            size_t off = (((size_t)vb * NCI8 + (co0 >> 3)) * 9216 + nl[i]) * 8 + (co0 & 7);
            *(ushort4*)(&co1[off]) = pk;
        }
    }
}

// ---------------------------------------------------------------------------
// K4a: BN partial stats. grid = 72 groups (v,c8) x 16 chunks = 1152 blocks.
// Each block sums 1152 of the 18432 samples for its 8 channels.
// part[blk][0..7] = sum, part[blk][8..15] = sumsq.
// ---------------------------------------------------------------------------
__global__ __launch_bounds__(256) void k_stats1(const unsigned short* __restrict__ co1,
                                                float* __restrict__ part) {
    int g = blockIdx.x >> 4;           // v*NCI8 + c8
    int chunk = blockIdx.x & 15;
    int v = g / NCI8;
    int c8 = g % NCI8;
    int t = threadIdx.x;

    float s[8] = {0,0,0,0,0,0,0,0}, ss[8] = {0,0,0,0,0,0,0,0};
    int m0 = chunk * 1152;             // 9216/1152 = 8 -> chunks don't cross bb
    for (int m = m0 + t; m < m0 + 1152; m += 256) {
        int bb = m / 9216;
        int n = m - bb * 9216;
        const unsigned short* p = co1 + (((size_t)(v * 2 + bb) * NCI8 + c8) * 9216 + n) * 8;
        uint4 raw = *(const uint4*)p;
        float f[8];
        unpack8(raw, f);
#pragma unroll
        for (int j = 0; j < 8; ++j) { s[j] += f[j]; ss[j] += f[j] * f[j]; }
    }
#pragma unroll
    for (int off = 1; off < 64; off <<= 1) {
#pragma unroll
        for (int j = 0; j < 8; ++j) {
            s[j]  += __shfl_xor(s[j],  off);
            ss[j] += __shfl_xor(ss[j], off);
        }
    }
    __shared__ float rs[4][8], rss[4][8];
    int wv = t >> 6;
    if ((t & 63) == 0) {
#pragma unroll
        for (int j = 0; j < 8; ++j) { rs[wv][j] = s[j]; rss[wv][j] = ss[j]; }
    }
    __syncthreads();
    if (t < 8) {
        int j = t;
        part[(size_t)blockIdx.x * 16 + j]     = rs[0][j] + rs[1][j] + rs[2][j] + rs[3][j];
        part[(size_t)blockIdx.x * 16 + 8 + j] = rss[0][j] + rss[1][j] + rss[2][j] + rss[3][j];
    }
}

// ---------------------------------------------------------------------------
// K4b: finalize stats -> per (v,c) scale/shift. 72 blocks x 1 wave.
// ---------------------------------------------------------------------------
__global__ __launch_bounds__(64) void k_stats2(const float* __restrict__ part,
                                               const float* __restrict__ gamma,
                                               const float* __restrict__ beta,
                                               float* __restrict__ scale,
                                               float* __restrict__ shift) {
    int g = blockIdx.x;                // v*NCI8 + c8
    int t = threadIdx.x;
    int j = t & 7, c = t >> 3;         // c in 0..7 -> chunks c and c+8
    size_t b0 = ((size_t)g * 16 + c) * 16;
    size_t b1 = ((size_t)g * 16 + c + 8) * 16;
    float S  = part[b0 + j]     + part[b1 + j];
    float SS = part[b0 + 8 + j] + part[b1 + 8 + j];
#pragma unroll
    for (int off = 8; off < 64; off <<= 1) {
        S  += __shfl_xor(S,  off);
        SS += __shfl_xor(SS, off);
    }
    if (t < 8) {
        int v = g / NCI8, c8 = g % NCI8;
        const float invN = 1.0f / (float)(Bn * THn * TWn);
        float mu = S * invN;
        float var = SS * invN - mu * mu;
        float rstd = rsqrtf(fmaxf(var, 0.0f) + EPSf);
        int ch = c8 * 8 + j;
        float sc = rstd * gamma[ch];
        scale[v * 96 + ch] = sc;
        shift[v * 96 + ch] = beta[ch] - mu * sc;
    }
}

// ---------------------------------------------------------------------------
// K5: fused BN + exact GELU (branchless erf) + conv2 1x1 MFMA + bias +
//     transpose to out (b,v,co,y,x) fp32. Wave = 16 n x 96 co -> 1728 blocks
//     (6.75 waves/SIMD). 18 MFMA/wave, 24 GELU/thread.
// ---------------------------------------------------------------------------
__global__ __launch_bounds__(256) void k_conv2(const unsigned short* __restrict__ co1,
                                               const unsigned short* __restrict__ wCP,
                                               const float* __restrict__ scale,
                                               const float* __restrict__ shift,
                                               const float* __restrict__ b2,
                                               float* __restrict__ out) {
    __shared__ float ssc[96], ssh[96], sbias[96];

    int blk = blockIdx.x;
    int n0 = blk * 64;                 // 9216 % 64 == 0 -> single vb
    int vb = n0 / 9216;
    int nl0 = n0 - vb * 9216;
    int v = vb >> 1, b = vb & 1;

    int t = threadIdx.x;
    int wv = t >> 6;
    int l = t & 63;
    int l15 = l & 15, q = l >> 4;

    if (t < 96) {
        ssc[t] = scale[v * 96 + t];
        ssh[t] = shift[v * 96 + t];
        sbias[t] = b2[t];
    }
    __syncthreads();

    int n = nl0 + wv * 16 + l15;

    f4v acc[6];
#pragma unroll
    for (int mt = 0; mt < 6; ++mt) acc[mt] = (f4v){0.f, 0.f, 0.f, 0.f};

#pragma unroll
    for (int ks = 0; ks < 3; ++ks) {
        int ci8 = ks * 4 + q;
        int ci0 = ci8 * 8;
        float sc[8], sh[8];
#pragma unroll
        for (int j = 0; j < 8; ++j) { sc[j] = ssc[ci0 + j]; sh[j] = ssh[ci0 + j]; }

        const unsigned short* pb = co1 + (((size_t)vb * NCI8 + ci8) * 9216 + n) * 8;
        uint4 raw = *(const uint4*)pb;
        float f[8];
        unpack8(raw, f);
        unsigned short o[8];
#pragma unroll
        for (int j = 0; j < 8; ++j) {
            float yv = f[j] * sc[j] + sh[j];
            o[j] = f2bf(gelu_f(yv));
        }
        s8v bfr = __builtin_bit_cast(s8v, pack8(o));

        const unsigned short* pa = wCP + ((size_t)ci8 * 96 + l15) * 8;
#pragma unroll
        for (int mt = 0; mt < 6; ++mt) {
            s8v a = *(const s8v*)(pa + (size_t)mt * (16 * 8));
            acc[mt] = __builtin_amdgcn_mfma_f32_16x16x32_bf16(a, bfr, acc[mt], 0, 0, 0);
        }
    }

    size_t obase = ((size_t)(b * Vn + v) * Cn) * 9216;
#pragma unroll
    for (int mt = 0; mt < 6; ++mt) {
        int co0 = mt * 16 + q * 4;
#pragma unroll
        for (int reg = 0; reg < 4; ++reg) {
            int co = co0 + reg;
            out[obase + (size_t)co * 9216 + n] = acc[mt][reg] + sbias[co];
        }
    }
}

// ---------------------------------------------------------------------------
extern "C" void kernel_launch(void* const* d_in, const int* in_sizes, int n_in,
                              void* d_out, int out_size, void* d_ws, size_t ws_size,
                              hipStream_t stream) {
    const float* tokens = (const float*)d_in[0];
    const float* angles = (const float*)d_in[1];
    const float* w1     = (const float*)d_in[2];
    const float* gamma  = (const float*)d_in[3];
    const float* beta   = (const float*)d_in[4];
    const float* w2     = (const float*)d_in[5];
    const float* b2     = (const float*)d_in[6];
    float* out = (float*)d_out;

    // workspace layout (bytes) — tokB aliases [rz .. co1) (dead after k_feat);
    // stats partials alias featP (dead after k_resize).
    char* ws = (char*)d_ws;
    unsigned short* featP = (unsigned short*)(ws);                //  5,308,416
    float* part = (float*)(ws);                                   //     73,728 (alias, featP dead)
    unsigned short* tokB  = (unsigned short*)(ws + 5308416);      // 42,467,328 (alias)
    unsigned short* rz    = (unsigned short*)(ws + 5308416);      // 22,127,616
    unsigned short* co1   = (unsigned short*)(ws + 27436032);     // 21,233,664
    unsigned short* wAtP  = (unsigned short*)(ws + 48669696);     //    165,888
    unsigned short* wCP   = (unsigned short*)(ws + 48835584);     //     18,432
    float* scale = (float*)(ws + 48854016);                       //      2,304
    float* shift = (float*)(ws + 48856320);                       //      2,304

    k_prep<<<360, 256, 0, stream>>>(w1, w2, wAtP, wCP);
    k_tok<<<10368, 256, 0, stream>>>(tokens, tokB);
    k_feat<<<1296, 256, 0, stream>>>(tokB, angles, featP);
    hipMemsetAsync(rz, 0, RZ_BYTES, stream);      // tokB dead; zero halo
    k_resize<<<5184, 256, 0, stream>>>(featP, rz);
    k_conv1<<<864, 256, 0, stream>>>(rz, wAtP, co1);
    k_stats1<<<1152, 256, 0, stream>>>(co1, part);
    k_stats2<<<72, 64, 0, stream>>>(part, gamma, beta, scale, shift);
    k_conv2<<<1728, 256, 0, stream>>>(co1, wCP, scale, shift, b2, out);
}